// Round 8
// baseline (187.236 us; speedup 1.0000x reference)
//
#include <hip/hip_runtime.h>
#include <math.h>

#define D_MODEL 1024
#define D_STATE 16
#define D_INNER 2048
#define DT_RANK 64
#define BATCH 2
#define SEQ 1024
#define NTOK (BATCH*SEQ)   // 2048 tokens
#define NC 32              // scan chunks
#define TC 32              // steps per chunk (SEQ/NC)

typedef __attribute__((ext_vector_type(8))) short short8;
typedef __attribute__((ext_vector_type(4))) float f32x4;

__device__ __forceinline__ float siluf(float x){ return x / (1.0f + __expf(-x)); }
__device__ __forceinline__ float softplusf(float x){ return x > 20.f ? x : log1pf(__expf(x)); }

__device__ __forceinline__ unsigned short f2bf(float f){
    unsigned int x = __float_as_uint(f);
    unsigned int r = (x + 0x7FFFu + ((x >> 16) & 1u)) >> 16;   // RNE
    return (unsigned short)r;
}
__device__ __forceinline__ float bf2f(unsigned short u){
    return __uint_as_float(((unsigned int)u) << 16);
}

// async HBM -> LDS, 16 B per lane. LDS dest is wave-uniform base + lane*16.
__device__ __forceinline__ void gl_lds16(const unsigned short* g, unsigned short* l)
{
    __builtin_amdgcn_global_load_lds(
        (const __attribute__((address_space(1))) unsigned int*)g,
        (__attribute__((address_space(3))) unsigned int*)l, 16, 0, 0);
}

// ---------------------------------------------------------------------------
// Fused fp32 -> bf16 conversion of all 5 tensors in ONE launch.
// ---------------------------------------------------------------------------
#define CR0 524288            // x            (2,097,152 f)
#define CR1 1572864           // + in_proj_w  (4,194,304 f)
#define CR2 1622016           // + x_proj_w   (196,608 f)
#define CR3 1654784           // + dt_proj_w  (131,072 f)
#define CR4 2179072           // + out_proj_w (2,097,152 f)   total float4s
__global__ __launch_bounds__(256)
void cvt_all(const float* __restrict__ s0, const float* __restrict__ s1,
             const float* __restrict__ s2, const float* __restrict__ s3,
             const float* __restrict__ s4,
             unsigned short* __restrict__ d0, unsigned short* __restrict__ d1,
             unsigned short* __restrict__ d2, unsigned short* __restrict__ d3,
             unsigned short* __restrict__ d4)
{
    int i = blockIdx.x * 256 + threadIdx.x;    // float4 index
    const float* s; unsigned short* dd; int base;
    if      (i < CR0) { s = s0; dd = d0; base = 0;   }
    else if (i < CR1) { s = s1; dd = d1; base = CR0; }
    else if (i < CR2) { s = s2; dd = d2; base = CR1; }
    else if (i < CR3) { s = s3; dd = d3; base = CR2; }
    else              { s = s4; dd = d4; base = CR3; }
    int j = (i - base) * 4;
    float4 v = *reinterpret_cast<const float4*>(&s[j]);
    ushort4 o;
    o.x = f2bf(v.x); o.y = f2bf(v.y); o.z = f2bf(v.z); o.w = f2bf(v.w);
    *reinterpret_cast<ushort4*>(&dd[j]) = o;
}

// ---------------------------------------------------------------------------
// 2-phase double-buffered bf16 MFMA GEMM: C[M x N] = A[M x K] @ W[N x K]^T.
// BM=BN=128, BK=32, 256 thr = 4 waves (2x2), wave = 64x64 = 16 MFMA/K-step.
// global_load_lds width-16 staging; prefetch buf^1 while computing buf.
// K % 64 == 0 required. Bijective XCD swizzle; blockIdx.z = split-K chunk,
// partials at C + z*M*ldc.
// EPI==1: softplus(acc+bias[n]).  OB==1: bf16 output.  NVALID>0: col guard.
// ---------------------------------------------------------------------------
template<int EPI, int OB, int NVALID>
__global__ __launch_bounds__(256)
void gemm128(const unsigned short* __restrict__ A, int lda,
             const unsigned short* __restrict__ W, int ldw,
             const float* __restrict__ bias,
             void* __restrict__ Cv, int ldc,
             int M, int K)
{
    __shared__ __align__(16) unsigned short As[2][128 * 32];
    __shared__ __align__(16) unsigned short Ws[2][128 * 32];
    float* Cf = (float*)Cv;
    unsigned short* Cb = (unsigned short*)Cv;
    const int tid = threadIdx.x;

    // XCD-aware bijective remap (m204 general form)
    const int nwg = gridDim.x * gridDim.y;
    int orig = blockIdx.y * gridDim.x + blockIdx.x;
    const int q = nwg >> 3, r = nwg & 7;
    int xcd = orig & 7, sub = orig >> 3;
    int wg = (xcd < r ? xcd * (q + 1) : r * (q + 1) + (xcd - r) * q) + sub;
    const int m0 = (wg / gridDim.x) * 128;
    const int n0 = (wg % gridDim.x) * 128;

    const size_t kbase = (size_t)blockIdx.z * K;
    const size_t zoff = (size_t)blockIdx.z * M * ldc;
    Cf += zoff; Cb += zoff;

    const int wave = tid >> 6, lane = tid & 63;
    const int wr = wave >> 1, wc = wave & 1;
    const int lr = lane & 15, lg = lane >> 4;

    // staging geometry: wave covers rows [wave*32, wave*32+32), 2 insts of 16 rows
    const int gr = lane >> 2;            // 0..15 row within inst
    const int gc = (lane & 3) * 8;       // col elems (16B)
    const unsigned short* Ab = A + kbase + gc + (size_t)(m0 + wave * 32 + gr) * lda;
    const unsigned short* Wb = W + kbase + gc + (size_t)(n0 + wave * 32 + gr) * ldw;
    const int lo = (wave * 32) * 32;     // wave-uniform LDS offset

    f32x4 acc[4][4];
#pragma unroll
    for (int i = 0; i < 4; i++)
#pragma unroll
        for (int j = 0; j < 4; j++) acc[i][j] = (f32x4)0.f;

    auto STAGE = [&](int buf, int kk) {
        gl_lds16(Ab + kk,            &As[buf][lo]);
        gl_lds16(Ab + kk + 16 * lda, &As[buf][lo + 16 * 32]);
        gl_lds16(Wb + kk,            &Ws[buf][lo]);
        gl_lds16(Wb + kk + 16 * ldw, &Ws[buf][lo + 16 * 32]);
    };
    auto COMPUTE = [&](int buf) {
        short8 af[4], bfr[4];
#pragma unroll
        for (int i = 0; i < 4; i++)
            af[i] = *reinterpret_cast<const short8*>(&As[buf][(wr * 64 + i * 16 + lr) * 32 + lg * 8]);
#pragma unroll
        for (int j = 0; j < 4; j++)
            bfr[j] = *reinterpret_cast<const short8*>(&Ws[buf][(wc * 64 + j * 16 + lr) * 32 + lg * 8]);
#pragma unroll
        for (int i = 0; i < 4; i++)
#pragma unroll
            for (int j = 0; j < 4; j++)
                acc[i][j] = __builtin_amdgcn_mfma_f32_16x16x32_bf16(af[i], bfr[j], acc[i][j], 0, 0, 0);
    };

    STAGE(0, 0);
    __syncthreads();                       // buf0 ready (vmcnt0 + barrier)
    for (int k0 = 0; k0 < K; k0 += 64) {
        if (k0 + 32 < K) STAGE(1, k0 + 32);   // prefetch in flight under MFMA
        COMPUTE(0);
        __syncthreads();
        if (k0 + 64 < K) STAGE(0, k0 + 64);
        COMPUTE(1);
        __syncthreads();
    }

#pragma unroll
    for (int i = 0; i < 4; i++) {
#pragma unroll
        for (int j = 0; j < 4; j++) {
            int col = n0 + wc * 64 + j * 16 + lr;
            if (NVALID > 0 && col >= NVALID) continue;
            int rbase = m0 + wr * 64 + i * 16 + lg * 4;
#pragma unroll
            for (int q2 = 0; q2 < 4; q2++) {
                float v = acc[i][j][q2];
                if (EPI == 1) v = softplusf(v + bias[col]);
                if (OB) Cb[(size_t)(rbase + q2) * ldc + col] = f2bf(v);
                else    Cf[(size_t)(rbase + q2) * ldc + col] = v;
            }
        }
    }
}

// ---------------------------------------------------------------------------
// Causal depthwise conv (width 4) + SiLU -> bf16, reading the SUM of the two
// in_proj split-K bf16 partials. 4 channels/thread (ushort4 loads).
// ---------------------------------------------------------------------------
__global__ __launch_bounds__(256)
void conv_silu4(const unsigned short* __restrict__ xzp, const float* __restrict__ cw,
                const float* __restrict__ cb, unsigned short* __restrict__ u)
{
    const size_t PS = (size_t)NTOK * 4096;            // partial stride
    int idx = blockIdx.x * 256 + threadIdx.x;         // quad index: tok*512 + cq
    int cq  = idx & 511;
    int c0  = cq * 4;                                 // channel quad base (<2048)
    int tok = idx >> 9;                               // 0..2047
    int l   = tok & (SEQ - 1);

    float4 w0 = *reinterpret_cast<const float4*>(&cw[(c0 + 0) * 4]);
    float4 w1 = *reinterpret_cast<const float4*>(&cw[(c0 + 1) * 4]);
    float4 w2 = *reinterpret_cast<const float4*>(&cw[(c0 + 2) * 4]);
    float4 w3 = *reinterpret_cast<const float4*>(&cw[(c0 + 3) * 4]);
    float4 bv = *reinterpret_cast<const float4*>(&cb[c0]);
    float acc0 = bv.x, acc1 = bv.y, acc2 = bv.z, acc3 = bv.w;

#pragma unroll
    for (int k = 0; k < 4; k++) {
        int lk = l - 3 + k;
        if (lk >= 0) {
            size_t base = (size_t)(tok - 3 + k) * 4096 + c0;
            ushort4 a = *reinterpret_cast<const ushort4*>(&xzp[base]);
            ushort4 b = *reinterpret_cast<const ushort4*>(&xzp[PS + base]);
            float x0 = bf2f(a.x) + bf2f(b.x);
            float x1 = bf2f(a.y) + bf2f(b.y);
            float x2 = bf2f(a.z) + bf2f(b.z);
            float x3 = bf2f(a.w) + bf2f(b.w);
            acc0 = fmaf(((const float*)&w0)[k], x0, acc0);
            acc1 = fmaf(((const float*)&w1)[k], x1, acc1);
            acc2 = fmaf(((const float*)&w2)[k], x2, acc2);
            acc3 = fmaf(((const float*)&w3)[k], x3, acc3);
        }
    }
    ushort4 o;
    o.x = f2bf(siluf(acc0)); o.y = f2bf(siluf(acc1));
    o.z = f2bf(siluf(acc2)); o.w = f2bf(siluf(acc3));
    *reinterpret_cast<ushort4*>(&u[(size_t)tok * D_INNER + c0]) = o;
}

// ---------------------------------------------------------------------------
// reduce 16 split-K partials -> xdbl fp32; first 64 cols also -> dt_bf bf16
// ---------------------------------------------------------------------------
__global__ __launch_bounds__(256)
void reduce_xproj(const float* __restrict__ part, float* __restrict__ xdbl,
                  unsigned short* __restrict__ dt_bf)
{
    int idx = blockIdx.x * 256 + threadIdx.x;   // m*96 + c
    float s = 0.f;
#pragma unroll
    for (int z = 0; z < 16; z++) s += part[(size_t)z * NTOK * 96 + idx];
    xdbl[idx] = s;
    int c = idx % 96, m = idx / 96;
    if (c < DT_RANK) dt_bf[m * DT_RANK + c] = f2bf(s);
}

// ---------------------------------------------------------------------------
// Chunked selective scan, transposed mapping (thread owns d, 16 states in reg)
// ---------------------------------------------------------------------------
__global__ __launch_bounds__(256)
void scan_phase1(const unsigned short* __restrict__ delta, const unsigned short* __restrict__ u,
                 const float* __restrict__ xdbl,  const float* __restrict__ A_log,
                 float* __restrict__ P, float* __restrict__ Q)
{
    __shared__ float sB[TC][16];
    const int tid = threadIdx.x;
    const int dblk = blockIdx.x & 7;
    const int cc = (blockIdx.x >> 3) & (NC - 1);
    const int b  = blockIdx.x >> 8;
    const int d  = dblk * 256 + tid;
    const int t0 = cc * TC;

    float A[16];
#pragma unroll
    for (int i = 0; i < 4; i++) {
        float4 al = *reinterpret_cast<const float4*>(&A_log[d * 16 + i * 4]);
        A[i*4+0] = -__expf(al.x); A[i*4+1] = -__expf(al.y);
        A[i*4+2] = -__expf(al.z); A[i*4+3] = -__expf(al.w);
    }
    for (int e = tid; e < TC * 16; e += 256) {
        int t = e >> 4, j = e & 15;
        sB[t][j] = xdbl[((size_t)b * SEQ + t0 + t) * 96 + DT_RANK + j];
    }
    __syncthreads();

    float h[16];
#pragma unroll
    for (int n = 0; n < 16; n++) h[n] = 0.f;
    float sum = 0.f;
#pragma unroll 4
    for (int t = 0; t < TC; t++) {
        size_t tok = (size_t)b * SEQ + t0 + t;
        float dv = bf2f(delta[tok * D_INNER + d]);
        float uv = bf2f(u[tok * D_INNER + d]);
        sum += dv;
        float du = dv * uv;
#pragma unroll
        for (int n = 0; n < 16; n++)
            h[n] = fmaf(__expf(dv * A[n]), h[n], du * sB[t][n]);
    }
    size_t off = ((size_t)(cc * BATCH + b) * D_INNER + d) * 16;
#pragma unroll
    for (int i = 0; i < 4; i++) {
        float4 pv = make_float4(__expf(A[i*4+0]*sum), __expf(A[i*4+1]*sum),
                                __expf(A[i*4+2]*sum), __expf(A[i*4+3]*sum));
        *reinterpret_cast<float4*>(&P[off + i*4]) = pv;
        *reinterpret_cast<float4*>(&Q[off + i*4]) =
            make_float4(h[i*4+0], h[i*4+1], h[i*4+2], h[i*4+3]);
    }
}

__global__ __launch_bounds__(256)
void scan_phase2(const float* __restrict__ P, float* __restrict__ Q)
{
    int idx = blockIdx.x * 256 + threadIdx.x;      // b*32768 + d*16 + n
    int b = idx >> 15, rem = idx & 32767;
    float h = 0.f;
#pragma unroll
    for (int cc = 0; cc < NC; cc++) {
        size_t off = (size_t)(cc * BATCH + b) * (D_INNER * D_STATE) + rem;
        float p = P[off], q = Q[off];
        Q[off] = h;                                 // H_in for chunk cc
        h = fmaf(p, h, q);
    }
}

__global__ __launch_bounds__(256)
void scan_phase3(const unsigned short* __restrict__ delta, const unsigned short* __restrict__ u,
                 const unsigned short* __restrict__ xzp, const float* __restrict__ xdbl,
                 const float* __restrict__ A_log, const float* __restrict__ Dp,
                 const float* __restrict__ Hin,   unsigned short* __restrict__ yg)
{
    __shared__ float sB[TC][16], sC[TC][16];
    const size_t PS = (size_t)NTOK * 4096;
    const int tid = threadIdx.x;
    const int dblk = blockIdx.x & 7;
    const int cc = (blockIdx.x >> 3) & (NC - 1);
    const int b  = blockIdx.x >> 8;
    const int d  = dblk * 256 + tid;
    const int t0 = cc * TC;

    float A[16];
#pragma unroll
    for (int i = 0; i < 4; i++) {
        float4 al = *reinterpret_cast<const float4*>(&A_log[d * 16 + i * 4]);
        A[i*4+0] = -__expf(al.x); A[i*4+1] = -__expf(al.y);
        A[i*4+2] = -__expf(al.z); A[i*4+3] = -__expf(al.w);
    }
    const float Dcoef = Dp[d];
    for (int e = tid; e < TC * 16; e += 256) {
        int t = e >> 4, j = e & 15;
        size_t tok = (size_t)b * SEQ + t0 + t;
        sB[t][j] = xdbl[tok * 96 + DT_RANK + j];
        sC[t][j] = xdbl[tok * 96 + DT_RANK + D_STATE + j];
    }
    float h[16];
    {
        size_t off = ((size_t)(cc * BATCH + b) * D_INNER + d) * 16;
#pragma unroll
        for (int i = 0; i < 4; i++) {
            float4 hv = *reinterpret_cast<const float4*>(&Hin[off + i*4]);
            h[i*4+0] = hv.x; h[i*4+1] = hv.y; h[i*4+2] = hv.z; h[i*4+3] = hv.w;
        }
    }
    __syncthreads();

#pragma unroll 4
    for (int t = 0; t < TC; t++) {
        size_t tok = (size_t)b * SEQ + t0 + t;
        float dv = bf2f(delta[tok * D_INNER + d]);
        float uv = bf2f(u[tok * D_INNER + d]);
        size_t zi = tok * 4096 + D_INNER + d;
        float zv = bf2f(xzp[zi]) + bf2f(xzp[PS + zi]);   // sum of split-K partials
        float du = dv * uv;
        float y = 0.f;
#pragma unroll
        for (int n = 0; n < 16; n++) {
            h[n] = fmaf(__expf(dv * A[n]), h[n], du * sB[t][n]);
            y = fmaf(h[n], sC[t][n], y);
        }
        y += uv * Dcoef;
        yg[tok * D_INNER + d] = f2bf(y * siluf(zv));
    }
}

// ---------------------------------------------------------------------------
// Residual + 8-way bf16 split-K reduce + LayerNorm. One block per token.
// ---------------------------------------------------------------------------
__global__ __launch_bounds__(256)
void ln8_kernel(const float* __restrict__ x, const unsigned short* __restrict__ p,
                const float* __restrict__ w, const float* __restrict__ bsc,
                float* __restrict__ out)
{
    __shared__ float red[2][4];
    const int t = blockIdx.x;
    const size_t base = (size_t)t * D_MODEL;
    const size_t S = (size_t)NTOK * D_MODEL;
    const int tid = threadIdx.x;
    const int c0 = tid * 4;
    float4 xv = *reinterpret_cast<const float4*>(&x[base + c0]);
    float v[4] = {xv.x, xv.y, xv.z, xv.w};
#pragma unroll
    for (int z = 0; z < 8; z++) {
        ushort4 pv = *reinterpret_cast<const ushort4*>(&p[z * S + base + c0]);
        v[0] += bf2f(pv.x); v[1] += bf2f(pv.y);
        v[2] += bf2f(pv.z); v[3] += bf2f(pv.w);
    }
    float s = 0.f, s2 = 0.f;
#pragma unroll
    for (int i = 0; i < 4; i++) { s += v[i]; s2 = fmaf(v[i], v[i], s2); }
#pragma unroll
    for (int off = 32; off >= 1; off >>= 1) {
        s  += __shfl_down(s,  off);
        s2 += __shfl_down(s2, off);
    }
    int lane = tid & 63, wid = tid >> 6;
    if (lane == 0) { red[0][wid] = s; red[1][wid] = s2; }
    __syncthreads();
    float S1 = red[0][0] + red[0][1] + red[0][2] + red[0][3];
    float S2 = red[1][0] + red[1][1] + red[1][2] + red[1][3];
    float mu  = S1 * (1.f / D_MODEL);
    float var = S2 * (1.f / D_MODEL) - mu * mu;
    float rstd = rsqrtf(var + 1e-5f);
    float4 wv = *reinterpret_cast<const float4*>(&w[c0]);
    float4 bv = *reinterpret_cast<const float4*>(&bsc[c0]);
    float4 ov;
    ov.x = (v[0] - mu) * rstd * wv.x + bv.x;
    ov.y = (v[1] - mu) * rstd * wv.y + bv.y;
    ov.z = (v[2] - mu) * rstd * wv.z + bv.z;
    ov.w = (v[3] - mu) * rstd * wv.w + bv.w;
    *reinterpret_cast<float4*>(&out[base + c0]) = ov;
}

// ---------------------------------------------------------------------------
extern "C" void kernel_launch(void* const* d_in, const int* in_sizes, int n_in,
                              void* d_out, int out_size, void* d_ws, size_t ws_size,
                              hipStream_t stream)
{
    const float* x         = (const float*)d_in[0];
    const float* in_proj_w = (const float*)d_in[1];
    const float* conv_w    = (const float*)d_in[2];
    const float* conv_b    = (const float*)d_in[3];
    const float* x_proj_w  = (const float*)d_in[4];
    const float* dt_proj_w = (const float*)d_in[5];
    const float* dt_proj_b = (const float*)d_in[6];
    const float* A_log     = (const float*)d_in[7];
    const float* D_param   = (const float*)d_in[8];
    const float* out_proj_w= (const float*)d_in[9];
    const float* ln_w      = (const float*)d_in[10];
    const float* ln_b      = (const float*)d_in[11];
    float* out = (float*)d_out;

    // ---- workspace layout (~89.8 MB; 93 MB proven available) ----
    // timeline: 1 cvt, 2 in_proj, 3 conv, 4 x_proj, 5 reduce, 6 dt_proj,
    //           7-9 scan, 10 out_proj, 11 ln
    unsigned short* xzp = (unsigned short*)d_ws;             // 2x NTOK*4096 u16 = 32MB (alive 2-9)
    float* xdbl = (float*)(xzp + (size_t)2 * NTOK * 4096);   // 0.75MB (alive 5-9)
    unsigned short* dlb = (unsigned short*)(xdbl + (size_t)NTOK * 96); // 8MB (alive 6-9)
    unsigned short* ub  = dlb + (size_t)NTOK * D_INNER;      // 8MB (alive 3-9)
    unsigned short* ygb = ub  + (size_t)NTOK * D_INNER;      // 8MB (alive 9-10)
    // ---- early region (all dead before scan phase1) ----
    unsigned short* xb  = ygb + (size_t)NTOK * D_INNER;      // 4MB   (dead after 2)
    unsigned short* wib = xb  + (size_t)NTOK * D_MODEL;      // 8MB   (dead after 2)
    unsigned short* wxb = wib + (size_t)4096 * 1024;         // 0.375 (dead after 4)
    unsigned short* wdb = wxb + (size_t)96 * 2048;           // 0.25  (dead after 6)
    unsigned short* dtb = wdb + (size_t)2048 * 64;           // 0.25  (dead after 6)
    float* xpart = (float*)(dtb + (size_t)NTOK * 64);        // 16x NTOK*96 f32 = 12MB (dead after 5)
    // P/Q (8MB each) alias the early region start (born step 7)
    float* Pbuf = (float*)xb;
    float* Qbuf = Pbuf + (size_t)NC * BATCH * D_INNER * D_STATE;
    // ---- wob after early region (alive through step 10) ----
    unsigned short* wob = (unsigned short*)(xpart + (size_t)16 * NTOK * 96); // 4MB
    // out_proj partials: 8 x NTOK*1024 u16 = 32MB alias xzp (dead after 9)
    unsigned short* opart = xzp;

    dim3 blk(256);

    // ---- fused fp32 -> bf16 conversions (one launch) ----
    cvt_all<<<dim3(CR4 / 256), blk, 0, stream>>>(
        x, in_proj_w, x_proj_w, dt_proj_w, out_proj_w,
        xb, wib, wxb, wdb, wob);

    // xz partials = x @ in_proj_w^T -> bf16 (M=2048, N=4096, K=1024, split-K=2)
    gemm128<0, 1, 0><<<dim3(4096 / 128, NTOK / 128, 2), blk, 0, stream>>>(
        xb, D_MODEL, wib, D_MODEL, nullptr, xzp, 2 * D_INNER, NTOK, D_MODEL / 2);

    // u = silu(conv(sum_z xzp[z][:, :2048]) + b) -> bf16
    conv_silu4<<<dim3((NTOK * 512) / 256), blk, 0, stream>>>(xzp, conv_w, conv_b, ub);

    // x_dbl partials = u @ x_proj_w^T  (split-K: 16 x 128; NVALID=96)
    gemm128<0, 0, 96><<<dim3(1, NTOK / 128, 16), blk, 0, stream>>>(
        ub, D_INNER, wxb, D_INNER, nullptr, xpart, 96, NTOK, 2048 / 16);

    reduce_xproj<<<dim3((NTOK * 96) / 256), blk, 0, stream>>>(xpart, xdbl, dtb);

    // delta = softplus(dt @ dt_proj_w^T + b) -> bf16  (M=2048, N=2048, K=64)
    gemm128<1, 1, 0><<<dim3(D_INNER / 128, NTOK / 128, 1), blk, 0, stream>>>(
        dtb, DT_RANK, wdb, DT_RANK, dt_proj_b, dlb, D_INNER, NTOK, DT_RANK);

    // ---- chunked selective scan (3 phases, transposed thread mapping) ----
    scan_phase1<<<dim3(BATCH * NC * (D_INNER / 256)), blk, 0, stream>>>(
        dlb, ub, xdbl, A_log, Pbuf, Qbuf);
    scan_phase2<<<dim3((BATCH * D_INNER * D_STATE) / 256), blk, 0, stream>>>(Pbuf, Qbuf);
    scan_phase3<<<dim3(BATCH * NC * (D_INNER / 256)), blk, 0, stream>>>(
        dlb, ub, xzp, xdbl, A_log, D_param, Qbuf, ygb);

    // out_proj partials -> bf16  (M=2048, N=1024, K=2048, split-K=8)
    gemm128<0, 1, 0><<<dim3(D_MODEL / 128, NTOK / 128, 8), blk, 0, stream>>>(
        ygb, D_INNER, wob, D_INNER, nullptr, opart, D_MODEL, NTOK, D_INNER / 8);

    // out = LN(x + sum_z opart[z])
    ln8_kernel<<<dim3(NTOK), blk, 0, stream>>>(x, opart, ln_w, ln_b, out);
}